// Round 1
// baseline (298.707 us; speedup 1.0000x reference)
//
#include <hip/hip_runtime.h>
#include <cstddef>

#define F 128    // F_IN == UNITS == 128
#define LDB 136  // LDS row stride in bf16 units: 128 + 8 pad

typedef __attribute__((ext_vector_type(8))) short bf16x8;
typedef __attribute__((ext_vector_type(4))) float f32x4;
typedef __attribute__((ext_vector_type(4))) unsigned int u32x4;

__device__ __forceinline__ unsigned short f2bf(float f) {
  unsigned int u = __float_as_uint(f);
  u += 0x7fffu + ((u >> 16) & 1u);  // round-to-nearest-even
  return (unsigned short)(u >> 16);
}

// ---------------------------------------------------------------------------
// Kernel 0: merged setup. Blocks [0, nbA) build row_ptr[N+1] from SORTED
// erow (edge-parallel); blocks [nbA, nbA+64) transpose+convert W -> Wt bf16.
// (~5 us measured-by-elimination; near floor.)
// ---------------------------------------------------------------------------
__global__ __launch_bounds__(256) void setup(const int* __restrict__ erow,
                                             int n_edges, int n_nodes, int nbA,
                                             int* __restrict__ row_ptr,
                                             const float* __restrict__ W,
                                             unsigned short* __restrict__ Wt) {
  const int bid = blockIdx.x;
  if (bid < nbA) {
    const int e = bid * 256 + threadIdx.x;
    if (e > n_edges) return;
    int r_lo, r_hi, val;
    if (e == 0) {
      r_lo = 0; r_hi = erow[0]; val = 0;
    } else if (e == n_edges) {
      r_lo = erow[n_edges - 1] + 1; r_hi = n_nodes; val = n_edges;
    } else {
      const int rp = erow[e - 1], rc = erow[e];
      r_lo = rp + 1; r_hi = rc; val = e;
    }
    for (int r = r_lo; r <= r_hi; ++r) row_ptr[r] = val;
  } else {
    const int idx = (bid - nbA) * 256 + threadIdx.x;  // 0..16383
    const int k = idx >> 7, n = idx & 127;
    Wt[n * F + k] = f2bf(W[idx]);
  }
}

// ---------------------------------------------------------------------------
// Kernel 1: H = bf16( X @ W ) via MFMA 16x16x32 bf16, stored FEATURE-BLOCKED:
//   H[fb][node][16]  (fb = feature block 0..7, 16 bf16 = 32 B per node/slice)
// so that spmm can keep one 3.2 MB slice resident per XCD L2.
// Side effect vs row-major: epilogue store is now fully coalesced — each
// (rt,ct) store covers a contiguous 512 B run per wave (16 rows x 32 B).
// ---------------------------------------------------------------------------
__global__ __launch_bounds__(256) void gemm_mfma(const float* __restrict__ X,
                                                 const unsigned short* __restrict__ Wt,
                                                 unsigned short* __restrict__ H,
                                                 int n_nodes) {
  __shared__ alignas(16) unsigned short Bs[128 * LDB];  // 34.8 KB
  const int tid = threadIdx.x;

  {  // stage Wt (bf16, k-contiguous): 2048 16B chunks, coalesced
    const uint4* src = (const uint4*)Wt;
    #pragma unroll
    for (int i = 0; i < 8; ++i) {
      const int idx = tid + i * 256;
      const int n = idx >> 4, c8 = idx & 15;
      *(uint4*)&Bs[n * LDB + c8 * 8] = src[idx];
    }
  }
  __syncthreads();

  const int wave = tid >> 6;
  const int lane = tid & 63;
  const int l15 = lane & 15;
  const int quad = lane >> 4;
  const int rbase = blockIdx.x * 128 + wave * 32;

  const float* xr[2];
  #pragma unroll
  for (int rt = 0; rt < 2; ++rt) {
    int r = rbase + rt * 16 + l15;
    if (r > n_nodes - 1) r = n_nodes - 1;
    xr[rt] = X + (size_t)r * F;
  }

  f32x4 acc[2][8] = {};

  #pragma unroll
  for (int ks = 0; ks < 4; ++ks) {
    const int k0 = ks * 32 + quad * 8;
    bf16x8 a[2], b[8];
    #pragma unroll
    for (int rt = 0; rt < 2; ++rt) {
      const float4 x0 = *(const float4*)(xr[rt] + k0);
      const float4 x1 = *(const float4*)(xr[rt] + k0 + 4);
      bf16x8 t;
      t[0] = (short)f2bf(x0.x); t[1] = (short)f2bf(x0.y);
      t[2] = (short)f2bf(x0.z); t[3] = (short)f2bf(x0.w);
      t[4] = (short)f2bf(x1.x); t[5] = (short)f2bf(x1.y);
      t[6] = (short)f2bf(x1.z); t[7] = (short)f2bf(x1.w);
      a[rt] = t;
    }
    #pragma unroll
    for (int ct = 0; ct < 8; ++ct)
      b[ct] = *(const bf16x8*)&Bs[(ct * 16 + l15) * LDB + k0];
    #pragma unroll
    for (int rt = 0; rt < 2; ++rt)
      #pragma unroll
      for (int ct = 0; ct < 8; ++ct)
        acc[rt][ct] = __builtin_amdgcn_mfma_f32_16x16x32_bf16(
            b[ct], a[rt], acc[rt][ct], 0, 0, 0);  // swapped -> transposed D
  }

  const size_t ns16 = (size_t)n_nodes * 16;  // shorts per feature slice
  #pragma unroll
  for (int rt = 0; rt < 2; ++rt) {
    const int row = rbase + rt * 16 + l15;
    if (row < n_nodes) {
      #pragma unroll
      for (int ct = 0; ct < 8; ++ct) {
        const unsigned int d0 = (unsigned int)f2bf(acc[rt][ct][0]) |
                                ((unsigned int)f2bf(acc[rt][ct][1]) << 16);
        const unsigned int d1 = (unsigned int)f2bf(acc[rt][ct][2]) |
                                ((unsigned int)f2bf(acc[rt][ct][3]) << 16);
        uint2 u; u.x = d0; u.y = d1;
        // feature-blocked: slice ct, node row, in-slice features quad*4..+3
        *(uint2*)&H[ns16 * ct + (size_t)row * 16 + quad * 4] = u;
      }
    }
  }
}

__device__ __forceinline__ void fma8(float* acc, uint4 h, float v) {
  acc[0] += v * __uint_as_float(h.x << 16);
  acc[1] += v * __uint_as_float(h.x & 0xffff0000u);
  acc[2] += v * __uint_as_float(h.y << 16);
  acc[3] += v * __uint_as_float(h.y & 0xffff0000u);
  acc[4] += v * __uint_as_float(h.z << 16);
  acc[5] += v * __uint_as_float(h.z & 0xffff0000u);
  acc[6] += v * __uint_as_float(h.w << 16);
  acc[7] += v * __uint_as_float(h.w & 0xffff0000u);
}

// ---------------------------------------------------------------------------
// Kernel 2: out[n, fb*16 .. fb*16+15] = sigmoid( sum_e val*H[fb][col] + bias )
// XCD-LOCAL GATHER: fb = blockIdx.x & 7 -> all blocks of slice fb land on the
// same XCD (round-robin dispatch), whose L2 (4 MB) holds the 3.2 MB slice
// H[fb][*][16]. Gathers become L2 hits instead of L3 service (prev kernel:
// FETCH 182 MB == 8 XCDs x full-H compulsory refill, 2.7 TB/s service bound).
// 2 lanes/node (16 B gather each), 32 nodes/wave, 4-edge aligned chunks with
// per-edge predication; edge streams + out stores are non-temporal so they
// don't evict the H slice. Arithmetic order per node identical to before.
// ---------------------------------------------------------------------------
__global__ __launch_bounds__(256) void spmm_bias_sigmoid(
    const int* __restrict__ row_ptr, const int* __restrict__ ecol,
    const float* __restrict__ eval, const unsigned short* __restrict__ H,
    const float* __restrict__ bias, float* __restrict__ out, int n_nodes) {
  const int fb = blockIdx.x & 7;   // feature slice == XCD id (bid % 8 RR)
  const int nb = blockIdx.x >> 3;
  const int lane = threadIdx.x & 63;
  const int wave = threadIdx.x >> 6;
  const int p = lane & 1;          // half-slice: in-slice features p*8..p*8+7
  const int node = nb * 128 + wave * 32 + (lane >> 1);
  const bool valid = (node < n_nodes);

  int lo = 0, deg = 0;
  if (valid) {
    lo = row_ptr[node];
    deg = row_ptr[node + 1] - lo;
  }

  const char* Hs = (const char*)H + (size_t)fb * ((size_t)n_nodes * 32) +
                   (size_t)(p * 16);

  float acc[8] = {};

  // Aligned 4-edge chunks over [lo & ~3, roundup4(lo+deg)); per-edge
  // predication via (e - lo) < deg. Guarantees 16B-aligned edge loads;
  // out-of-range slots gather a real (neighbor's) column with v=0 — cheap
  // L2 hits, no contribution. n_edges % 4 == 0 so chunks never run OOB.
  const int abase = lo & ~3;
  const int aend = (lo + deg + 3) & ~3;
  for (int e0 = abase; e0 < aend; e0 += 4) {
    const u32x4 cols = __builtin_nontemporal_load((const u32x4*)(ecol + e0));
    const f32x4 vals = __builtin_nontemporal_load((const f32x4*)(eval + e0));
    #pragma unroll
    for (int j = 0; j < 4; ++j) {
      const unsigned rel = (unsigned)(e0 + j - lo);
      const float v = (rel < (unsigned)deg) ? vals[j] : 0.f;
      const uint4 h = *(const uint4*)(Hs + ((size_t)cols[j] << 5));
      fma8(acc, h, v);
    }
  }

  if (valid) {
    const float* bp = bias + fb * 16 + p * 8;
    f32x4 o0, o1;
    o0[0] = 1.f / (1.f + expf(-(acc[0] + bp[0])));
    o0[1] = 1.f / (1.f + expf(-(acc[1] + bp[1])));
    o0[2] = 1.f / (1.f + expf(-(acc[2] + bp[2])));
    o0[3] = 1.f / (1.f + expf(-(acc[3] + bp[3])));
    o1[0] = 1.f / (1.f + expf(-(acc[4] + bp[4])));
    o1[1] = 1.f / (1.f + expf(-(acc[5] + bp[5])));
    o1[2] = 1.f / (1.f + expf(-(acc[6] + bp[6])));
    o1[3] = 1.f / (1.f + expf(-(acc[7] + bp[7])));
    float* op = out + (size_t)node * F + fb * 16 + p * 8;
    __builtin_nontemporal_store(o0, (f32x4*)op);
    __builtin_nontemporal_store(o1, (f32x4*)(op + 4));
  }
}

// ---------------------------------------------------------------------------
extern "C" void kernel_launch(void* const* d_in, const int* in_sizes, int n_in,
                              void* d_out, int out_size, void* d_ws, size_t ws_size,
                              hipStream_t stream) {
  const float* X    = (const float*)d_in[0];
  const int*   erow = (const int*)  d_in[1];
  const int*   ecol = (const int*)  d_in[2];
  const float* eval = (const float*)d_in[3];
  const float* W    = (const float*)d_in[4];
  const float* bias = (const float*)d_in[5];
  float* out = (float*)d_out;

  const int n_nodes = in_sizes[0] / F;  // 100000
  const int n_edges = in_sizes[1];      // 1600000

  // Workspace layout (16B aligned):
  //   H  : n_nodes*F bf16 (feature-blocked [8][n_nodes][16]) = 25,600,000 B
  //   rp : (n_nodes+1) int  =    400,004 B (padded to 16)
  //   Wt : F*F bf16         =     32,768 B
  char* ws = (char*)d_ws;
  unsigned short* H = (unsigned short*)ws;
  size_t off = (size_t)n_nodes * F * sizeof(unsigned short);
  int* row_ptr = (int*)(ws + off);
  off += ((size_t)(n_nodes + 1) * sizeof(int) + 15) & ~(size_t)15;
  unsigned short* Wt = (unsigned short*)(ws + off);

  const int nbA = (n_edges + 256) / 256;
  const int nbB = (F * F) / 256;  // 64
  setup<<<nbA + nbB, 256, 0, stream>>>(erow, n_edges, n_nodes, nbA, row_ptr,
                                       W, Wt);
  gemm_mfma<<<(n_nodes + 127) / 128, 256, 0, stream>>>(X, Wt, H, n_nodes);
  const int nbN = (n_nodes + 127) / 128;  // node blocks per slice
  spmm_bias_sigmoid<<<nbN * 8, 256, 0, stream>>>(
      row_ptr, ecol, eval, H, bias, out, n_nodes);
}

// Round 2
// 200.530 us; speedup vs baseline: 1.4896x; 1.4896x over previous
//
#include <hip/hip_runtime.h>
#include <cstddef>

#define F 128    // F_IN == UNITS == 128
#define LDB 136  // LDS row stride in bf16 units: 128 + 8 pad

typedef __attribute__((ext_vector_type(8))) short bf16x8;
typedef __attribute__((ext_vector_type(4))) float f32x4;

__device__ __forceinline__ unsigned short f2bf(float f) {
  unsigned int u = __float_as_uint(f);
  u += 0x7fffu + ((u >> 16) & 1u);  // round-to-nearest-even
  return (unsigned short)(u >> 16);
}

// ---------------------------------------------------------------------------
// Kernel 1 (merged): blocks [0, nbG) compute H = bf16(X @ W) via MFMA
// 16x16x32 bf16 (W converted fp32->bf16 transposed in-block from L2/L3-
// resident W, 64 KB — removes the separate setup launch's Wt dependency);
// blocks [nbG, nbG+nbA) build row_ptr[N+1] from SORTED erow (edge-parallel).
// row_ptr is only read by the NEXT launch, so no intra-launch ordering needed.
// Swapped-operand mfma -> D transposed: lane (quad,l15) holds node row
// rt*16+l15, features ct*16+quad*4+{0..3} -> one 8B store per (rt,ct).
// ---------------------------------------------------------------------------
__global__ __launch_bounds__(256) void gemm_rp(const float* __restrict__ X,
                                               const float* __restrict__ W,
                                               unsigned short* __restrict__ H,
                                               const int* __restrict__ erow,
                                               int* __restrict__ row_ptr,
                                               int n_nodes, int n_edges,
                                               int nbG) {
  if (blockIdx.x >= nbG) {  // ---- row_ptr builder blocks ----
    const int e = (blockIdx.x - nbG) * 256 + threadIdx.x;
    if (e > n_edges) return;
    int r_lo, r_hi, val;
    if (e == 0) {
      r_lo = 0; r_hi = erow[0]; val = 0;
    } else if (e == n_edges) {
      r_lo = erow[n_edges - 1] + 1; r_hi = n_nodes; val = n_edges;
    } else {
      const int rp = erow[e - 1], rc = erow[e];
      r_lo = rp + 1; r_hi = rc; val = e;
    }
    for (int r = r_lo; r <= r_hi; ++r) row_ptr[r] = val;
    return;
  }

  // ---- GEMM blocks ----
  __shared__ alignas(16) unsigned short Bs[128 * LDB];  // 34.8 KB
  const int tid = threadIdx.x;

  {  // stage W (fp32, k-major [k][n]) -> Bs[n][k] bf16, float4 per thread
    const float4* W4 = (const float4*)W;
    #pragma unroll
    for (int i = 0; i < 16; ++i) {
      const int idx = tid + i * 256;    // float4 index, 0..4095
      const int k = idx >> 5;           // 32 float4 per k-row
      const int n4 = (idx & 31) * 4;
      const float4 w = W4[idx];
      Bs[(n4 + 0) * LDB + k] = f2bf(w.x);
      Bs[(n4 + 1) * LDB + k] = f2bf(w.y);
      Bs[(n4 + 2) * LDB + k] = f2bf(w.z);
      Bs[(n4 + 3) * LDB + k] = f2bf(w.w);
    }
  }
  __syncthreads();

  const int wave = tid >> 6;
  const int lane = tid & 63;
  const int l15 = lane & 15;
  const int quad = lane >> 4;
  const int rbase = blockIdx.x * 128 + wave * 32;

  const float* xr[2];
  #pragma unroll
  for (int rt = 0; rt < 2; ++rt) {
    int r = rbase + rt * 16 + l15;
    if (r > n_nodes - 1) r = n_nodes - 1;
    xr[rt] = X + (size_t)r * F;
  }

  f32x4 acc[2][8] = {};

  #pragma unroll
  for (int ks = 0; ks < 4; ++ks) {
    const int k0 = ks * 32 + quad * 8;
    bf16x8 a[2], b[8];
    #pragma unroll
    for (int rt = 0; rt < 2; ++rt) {
      const float4 x0 = *(const float4*)(xr[rt] + k0);
      const float4 x1 = *(const float4*)(xr[rt] + k0 + 4);
      bf16x8 t;
      t[0] = (short)f2bf(x0.x); t[1] = (short)f2bf(x0.y);
      t[2] = (short)f2bf(x0.z); t[3] = (short)f2bf(x0.w);
      t[4] = (short)f2bf(x1.x); t[5] = (short)f2bf(x1.y);
      t[6] = (short)f2bf(x1.z); t[7] = (short)f2bf(x1.w);
      a[rt] = t;
    }
    #pragma unroll
    for (int ct = 0; ct < 8; ++ct)
      b[ct] = *(const bf16x8*)&Bs[(ct * 16 + l15) * LDB + k0];
    #pragma unroll
    for (int rt = 0; rt < 2; ++rt)
      #pragma unroll
      for (int ct = 0; ct < 8; ++ct)
        acc[rt][ct] = __builtin_amdgcn_mfma_f32_16x16x32_bf16(
            b[ct], a[rt], acc[rt][ct], 0, 0, 0);  // swapped -> transposed D
  }

  #pragma unroll
  for (int rt = 0; rt < 2; ++rt) {
    const int row = rbase + rt * 16 + l15;
    if (row < n_nodes) {
      #pragma unroll
      for (int ct = 0; ct < 8; ++ct) {
        const unsigned int d0 = (unsigned int)f2bf(acc[rt][ct][0]) |
                                ((unsigned int)f2bf(acc[rt][ct][1]) << 16);
        const unsigned int d1 = (unsigned int)f2bf(acc[rt][ct][2]) |
                                ((unsigned int)f2bf(acc[rt][ct][3]) << 16);
        uint2 u; u.x = d0; u.y = d1;
        *(uint2*)&H[(size_t)row * F + ct * 16 + quad * 4] = u;
      }
    }
  }
}

// ---------------------------------------------------------------------------
// Kernel 2: out[n,:] = sigmoid( sum_e val[e]*H[col[e],:] + bias ), H bf16.
// BEST MEASURED CONFIG (69.0 us): 4 nodes/wave, 16 lanes/node, one
// dwordx4 (16B) per lane per edge, cnt==16 chunk fully unrolled (16 gathers
// in flight). Plateau evidence: 4/8/16-deep MLP x 32-100% occ x 8/16B lanes
// all land 69-80 us at FETCH ~= per-XCD compulsory H refill (8 x 22.5 MB) —
// L2/L3-gather-service bound; columns uniform-random, no locality to mine.
// XCD feature-slicing variant (r1) REGRESSED to 182 us: 32 B node records
// inflate line-touches/edge 2 -> 8 and drop in-flight gathers 16 -> 4.
// Row-major 256 B rows + 16-lane gathers is the optimal access shape.
// ---------------------------------------------------------------------------
__global__ __launch_bounds__(256) void spmm_bias_sigmoid(
    const int* __restrict__ row_ptr, const int* __restrict__ ecol,
    const float* __restrict__ eval, const unsigned short* __restrict__ H,
    const float* __restrict__ bias, float* __restrict__ out, int n_nodes) {
  const int wave = threadIdx.x >> 6;
  const int lane = threadIdx.x & 63;
  const int g = lane >> 4;   // node slot within wave
  const int fl = lane & 15;  // feature-lane: features fl*8 .. fl*8+7
  const int node = blockIdx.x * 16 + wave * 4 + g;
  const bool valid = (node < n_nodes);

  const int lo = valid ? row_ptr[node] : 0;
  const int hi = valid ? row_ptr[node + 1] : 0;
  const int deg = hi - lo;

  int dmax = deg;
  dmax = max(dmax, __shfl_xor(dmax, 16, 64));
  dmax = max(dmax, __shfl_xor(dmax, 32, 64));

  const int bpbase = (lane & 48) * 4;  // byte idx of own group's lane 0
  const char* Hb = (const char*)H + fl * 16;

  float acc[8] = {};

#define SPMM_STEP(j)                                                        \
  {                                                                         \
    const int idx = bpbase + (j) * 4;                                       \
    const int ro = __builtin_amdgcn_ds_bpermute(idx, voff);                 \
    const float v = __int_as_float(                                         \
        __builtin_amdgcn_ds_bpermute(idx, __float_as_int(vv)));             \
    const uint4 h = *(const uint4*)(Hb + ro);                               \
    acc[0] += v * __uint_as_float(h.x << 16);                               \
    acc[1] += v * __uint_as_float(h.x & 0xffff0000u);                       \
    acc[2] += v * __uint_as_float(h.y << 16);                               \
    acc[3] += v * __uint_as_float(h.y & 0xffff0000u);                       \
    acc[4] += v * __uint_as_float(h.z << 16);                               \
    acc[5] += v * __uint_as_float(h.z & 0xffff0000u);                       \
    acc[6] += v * __uint_as_float(h.w << 16);                               \
    acc[7] += v * __uint_as_float(h.w & 0xffff0000u);                       \
  }

  for (int base = 0; base < dmax; base += 16) {
    int voff = 0;
    float vv = 0.f;
    if (base + fl < deg) {
      const int e = lo + base + fl;
      voff = ecol[e] << 8;  // byte offset of H row (c * 256B)
      vv = eval[e];
    }
    const int cnt = min(dmax - base, 16);
    if (cnt == 16) {
      #pragma unroll
      for (int j = 0; j < 16; ++j) SPMM_STEP(j)
    } else {
      #pragma unroll 4
      for (int j = 0; j < cnt; ++j) SPMM_STEP(j)
    }
  }
#undef SPMM_STEP

  if (valid) {
    const float4 b0 = *(const float4*)&bias[fl * 8];
    const float4 b1 = *(const float4*)&bias[fl * 8 + 4];
    float4 o0, o1;
    o0.x = 1.f / (1.f + expf(-(acc[0] + b0.x)));
    o0.y = 1.f / (1.f + expf(-(acc[1] + b0.y)));
    o0.z = 1.f / (1.f + expf(-(acc[2] + b0.z)));
    o0.w = 1.f / (1.f + expf(-(acc[3] + b0.w)));
    o1.x = 1.f / (1.f + expf(-(acc[4] + b1.x)));
    o1.y = 1.f / (1.f + expf(-(acc[5] + b1.y)));
    o1.z = 1.f / (1.f + expf(-(acc[6] + b1.z)));
    o1.w = 1.f / (1.f + expf(-(acc[7] + b1.w)));
    float* op = out + (size_t)node * F + fl * 8;
    *(float4*)op = o0;
    *(float4*)(op + 4) = o1;
  }
}

// ---------------------------------------------------------------------------
extern "C" void kernel_launch(void* const* d_in, const int* in_sizes, int n_in,
                              void* d_out, int out_size, void* d_ws, size_t ws_size,
                              hipStream_t stream) {
  const float* X    = (const float*)d_in[0];
  const int*   erow = (const int*)  d_in[1];
  const int*   ecol = (const int*)  d_in[2];
  const float* eval = (const float*)d_in[3];
  const float* W    = (const float*)d_in[4];
  const float* bias = (const float*)d_in[5];
  float* out = (float*)d_out;

  const int n_nodes = in_sizes[0] / F;  // 100000
  const int n_edges = in_sizes[1];      // 1600000

  // Workspace layout (16B aligned):
  //   H  : n_nodes*F bf16   = 25,600,000 B
  //   rp : (n_nodes+1) int  =    400,004 B
  char* ws = (char*)d_ws;
  unsigned short* H = (unsigned short*)ws;
  size_t off = (size_t)n_nodes * F * sizeof(unsigned short);
  int* row_ptr = (int*)(ws + off);

  const int nbG = (n_nodes + 127) / 128;   // 782 gemm blocks
  const int nbA = (n_edges + 256) / 256;   // 6251 row_ptr blocks
  gemm_rp<<<nbG + nbA, 256, 0, stream>>>(X, W, H, erow, row_ptr,
                                         n_nodes, n_edges, nbG);
  spmm_bias_sigmoid<<<(n_nodes + 15) / 16, 256, 0, stream>>>(
      row_ptr, ecol, eval, H, bias, out, n_nodes);
}

// Round 3
// 188.459 us; speedup vs baseline: 1.5850x; 1.0641x over previous
//
#include <hip/hip_runtime.h>
#include <cstddef>

#define F 128    // F_IN == UNITS == 128
#define LDB 136  // LDS row stride in bf16 units: 128 + 8 pad

typedef __attribute__((ext_vector_type(8))) short bf16x8;
typedef __attribute__((ext_vector_type(4))) float f32x4;

__device__ __forceinline__ unsigned short f2bf(float f) {
  unsigned int u = __float_as_uint(f);
  u += 0x7fffu + ((u >> 16) & 1u);  // round-to-nearest-even
  return (unsigned short)(u >> 16);
}

// ---------------------------------------------------------------------------
// Kernel 0: merged setup. Blocks [0, nbA) build row_ptr[N+1] from SORTED
// erow (edge-parallel); blocks [nbA, nbA+64) transpose+convert W -> Wt bf16.
// (~5 us measured-by-elimination; near floor.)
// NOTE (r2): folding the W conversion into each gemm block regressed
// (16-way LDS bank conflicts on scalar b16 writes x 782 blocks, +W re-reads:
// gemm 23 -> 37 us). Keep the one-shot Wt conversion here.
// ---------------------------------------------------------------------------
__global__ __launch_bounds__(256) void setup(const int* __restrict__ erow,
                                             int n_edges, int n_nodes, int nbA,
                                             int* __restrict__ row_ptr,
                                             const float* __restrict__ W,
                                             unsigned short* __restrict__ Wt) {
  const int bid = blockIdx.x;
  if (bid < nbA) {
    const int e = bid * 256 + threadIdx.x;
    if (e > n_edges) return;
    int r_lo, r_hi, val;
    if (e == 0) {
      r_lo = 0; r_hi = erow[0]; val = 0;
    } else if (e == n_edges) {
      r_lo = erow[n_edges - 1] + 1; r_hi = n_nodes; val = n_edges;
    } else {
      const int rp = erow[e - 1], rc = erow[e];
      r_lo = rp + 1; r_hi = rc; val = e;
    }
    for (int r = r_lo; r <= r_hi; ++r) row_ptr[r] = val;
  } else {
    const int idx = (bid - nbA) * 256 + threadIdx.x;  // 0..16383
    const int k = idx >> 7, n = idx & 127;
    Wt[n * F + k] = f2bf(W[idx]);
  }
}

// ---------------------------------------------------------------------------
// Kernel 1: H_bf16 = bf16( X @ W )  via MFMA 16x16x32 bf16.
// 18.0 us measured (r8 double-launch diagnostic) vs ~13 us memory floor.
// Swapped-operand mfma -> D transposed: lane (quad,l15) holds node row
// rt*16+l15, features ct*16+quad*4+{0..3} -> one 8B store per (rt,ct).
// ---------------------------------------------------------------------------
__global__ __launch_bounds__(256) void gemm_mfma(const float* __restrict__ X,
                                                 const unsigned short* __restrict__ Wt,
                                                 unsigned short* __restrict__ H,
                                                 int n_nodes) {
  __shared__ alignas(16) unsigned short Bs[128 * LDB];  // 34.8 KB
  const int tid = threadIdx.x;

  {  // stage Wt (bf16, k-contiguous): 2048 16B chunks, coalesced
    const uint4* src = (const uint4*)Wt;
    #pragma unroll
    for (int i = 0; i < 8; ++i) {
      const int idx = tid + i * 256;
      const int n = idx >> 4, c8 = idx & 15;
      *(uint4*)&Bs[n * LDB + c8 * 8] = src[idx];
    }
  }
  __syncthreads();

  const int wave = tid >> 6;
  const int lane = tid & 63;
  const int l15 = lane & 15;
  const int quad = lane >> 4;
  const int rbase = blockIdx.x * 128 + wave * 32;

  const float* xr[2];
  #pragma unroll
  for (int rt = 0; rt < 2; ++rt) {
    int r = rbase + rt * 16 + l15;
    if (r > n_nodes - 1) r = n_nodes - 1;
    xr[rt] = X + (size_t)r * F;
  }

  f32x4 acc[2][8] = {};

  #pragma unroll
  for (int ks = 0; ks < 4; ++ks) {
    const int k0 = ks * 32 + quad * 8;
    bf16x8 a[2], b[8];
    #pragma unroll
    for (int rt = 0; rt < 2; ++rt) {
      const float4 x0 = *(const float4*)(xr[rt] + k0);
      const float4 x1 = *(const float4*)(xr[rt] + k0 + 4);
      bf16x8 t;
      t[0] = (short)f2bf(x0.x); t[1] = (short)f2bf(x0.y);
      t[2] = (short)f2bf(x0.z); t[3] = (short)f2bf(x0.w);
      t[4] = (short)f2bf(x1.x); t[5] = (short)f2bf(x1.y);
      t[6] = (short)f2bf(x1.z); t[7] = (short)f2bf(x1.w);
      a[rt] = t;
    }
    #pragma unroll
    for (int ct = 0; ct < 8; ++ct)
      b[ct] = *(const bf16x8*)&Bs[(ct * 16 + l15) * LDB + k0];
    #pragma unroll
    for (int rt = 0; rt < 2; ++rt)
      #pragma unroll
      for (int ct = 0; ct < 8; ++ct)
        acc[rt][ct] = __builtin_amdgcn_mfma_f32_16x16x32_bf16(
            b[ct], a[rt], acc[rt][ct], 0, 0, 0);  // swapped -> transposed D
  }

  #pragma unroll
  for (int rt = 0; rt < 2; ++rt) {
    const int row = rbase + rt * 16 + l15;
    if (row < n_nodes) {
      #pragma unroll
      for (int ct = 0; ct < 8; ++ct) {
        const unsigned int d0 = (unsigned int)f2bf(acc[rt][ct][0]) |
                                ((unsigned int)f2bf(acc[rt][ct][1]) << 16);
        const unsigned int d1 = (unsigned int)f2bf(acc[rt][ct][2]) |
                                ((unsigned int)f2bf(acc[rt][ct][3]) << 16);
        uint2 u; u.x = d0; u.y = d1;
        *(uint2*)&H[(size_t)row * F + ct * 16 + quad * 4] = u;
      }
    }
  }
}

// ---------------------------------------------------------------------------
// Kernel 2: out[n,:] = sigmoid( sum_e val[e]*H[col[e],:] + bias ), H bf16.
// BEST MEASURED CONFIG (69.0 us, reproduced r0/r2): 4 nodes/wave, 16
// lanes/node, one dwordx4 (16B) per lane per edge, cnt==16 chunk fully
// unrolled (16 gathers in flight). Plateau evidence: 4/8/16-deep MLP x
// 32-100% occ x 8/16B lanes all land 69-80 us at FETCH ~= per-XCD compulsory
// H refill (8 x 22.5 MB) — L2-fill service bound (~2.6 Gline/s/XCD);
// columns uniform-random, no locality to mine.
// r1 XCD feature-slicing REGRESSED (182 us): 32 B records inflate
// line-touches/edge 2 -> 8, in-flight gathers 16 -> 4. fp8-H rejected by
// arithmetic: e4m3 step 32x bf16 -> absmax ~0.1-0.3 (bf16 predicts 0.012 =
// measured 0.0117). Row-major 256 B + 16-lane gathers is optimal shape.
// ---------------------------------------------------------------------------
__global__ __launch_bounds__(256) void spmm_bias_sigmoid(
    const int* __restrict__ row_ptr, const int* __restrict__ ecol,
    const float* __restrict__ eval, const unsigned short* __restrict__ H,
    const float* __restrict__ bias, float* __restrict__ out, int n_nodes) {
  const int wave = threadIdx.x >> 6;
  const int lane = threadIdx.x & 63;
  const int g = lane >> 4;   // node slot within wave
  const int fl = lane & 15;  // feature-lane: features fl*8 .. fl*8+7
  const int node = blockIdx.x * 16 + wave * 4 + g;
  const bool valid = (node < n_nodes);

  const int lo = valid ? row_ptr[node] : 0;
  const int hi = valid ? row_ptr[node + 1] : 0;
  const int deg = hi - lo;

  int dmax = deg;
  dmax = max(dmax, __shfl_xor(dmax, 16, 64));
  dmax = max(dmax, __shfl_xor(dmax, 32, 64));

  const int bpbase = (lane & 48) * 4;  // byte idx of own group's lane 0
  const char* Hb = (const char*)H + fl * 16;

  float acc[8] = {};

#define SPMM_STEP(j)                                                        \
  {                                                                         \
    const int idx = bpbase + (j) * 4;                                       \
    const int ro = __builtin_amdgcn_ds_bpermute(idx, voff);                 \
    const float v = __int_as_float(                                         \
        __builtin_amdgcn_ds_bpermute(idx, __float_as_int(vv)));             \
    const uint4 h = *(const uint4*)(Hb + ro);                               \
    acc[0] += v * __uint_as_float(h.x << 16);                               \
    acc[1] += v * __uint_as_float(h.x & 0xffff0000u);                       \
    acc[2] += v * __uint_as_float(h.y << 16);                               \
    acc[3] += v * __uint_as_float(h.y & 0xffff0000u);                       \
    acc[4] += v * __uint_as_float(h.z << 16);                               \
    acc[5] += v * __uint_as_float(h.z & 0xffff0000u);                       \
    acc[6] += v * __uint_as_float(h.w << 16);                               \
    acc[7] += v * __uint_as_float(h.w & 0xffff0000u);                       \
  }

  for (int base = 0; base < dmax; base += 16) {
    int voff = 0;
    float vv = 0.f;
    if (base + fl < deg) {
      const int e = lo + base + fl;
      voff = ecol[e] << 8;  // byte offset of H row (c * 256B)
      vv = eval[e];
    }
    const int cnt = min(dmax - base, 16);
    if (cnt == 16) {
      #pragma unroll
      for (int j = 0; j < 16; ++j) SPMM_STEP(j)
    } else {
      #pragma unroll 4
      for (int j = 0; j < cnt; ++j) SPMM_STEP(j)
    }
  }
#undef SPMM_STEP

  if (valid) {
    const float4 b0 = *(const float4*)&bias[fl * 8];
    const float4 b1 = *(const float4*)&bias[fl * 8 + 4];
    float4 o0, o1;
    o0.x = 1.f / (1.f + expf(-(acc[0] + b0.x)));
    o0.y = 1.f / (1.f + expf(-(acc[1] + b0.y)));
    o0.z = 1.f / (1.f + expf(-(acc[2] + b0.z)));
    o0.w = 1.f / (1.f + expf(-(acc[3] + b0.w)));
    o1.x = 1.f / (1.f + expf(-(acc[4] + b1.x)));
    o1.y = 1.f / (1.f + expf(-(acc[5] + b1.y)));
    o1.z = 1.f / (1.f + expf(-(acc[6] + b1.z)));
    o1.w = 1.f / (1.f + expf(-(acc[7] + b1.w)));
    float* op = out + (size_t)node * F + fl * 8;
    *(float4*)op = o0;
    *(float4*)(op + 4) = o1;
  }
}

// ---------------------------------------------------------------------------
extern "C" void kernel_launch(void* const* d_in, const int* in_sizes, int n_in,
                              void* d_out, int out_size, void* d_ws, size_t ws_size,
                              hipStream_t stream) {
  const float* X    = (const float*)d_in[0];
  const int*   erow = (const int*)  d_in[1];
  const int*   ecol = (const int*)  d_in[2];
  const float* eval = (const float*)d_in[3];
  const float* W    = (const float*)d_in[4];
  const float* bias = (const float*)d_in[5];
  float* out = (float*)d_out;

  const int n_nodes = in_sizes[0] / F;  // 100000
  const int n_edges = in_sizes[1];      // 1600000

  // Workspace layout (16B aligned):
  //   H  : n_nodes*F bf16   = 25,600,000 B
  //   rp : (n_nodes+1) int  =    400,004 B (padded to 16)
  //   Wt : F*F bf16         =     32,768 B
  char* ws = (char*)d_ws;
  unsigned short* H = (unsigned short*)ws;
  size_t off = (size_t)n_nodes * F * sizeof(unsigned short);
  int* row_ptr = (int*)(ws + off);
  off += ((size_t)(n_nodes + 1) * sizeof(int) + 15) & ~(size_t)15;
  unsigned short* Wt = (unsigned short*)(ws + off);

  const int nbA = (n_edges + 256) / 256;
  const int nbB = (F * F) / 256;  // 64
  setup<<<nbA + nbB, 256, 0, stream>>>(erow, n_edges, n_nodes, nbA, row_ptr,
                                       W, Wt);
  gemm_mfma<<<(n_nodes + 127) / 128, 256, 0, stream>>>(X, Wt, H, n_nodes);
  spmm_bias_sigmoid<<<(n_nodes + 15) / 16, 256, 0, stream>>>(
      row_ptr, ecol, eval, H, bias, out, n_nodes);
}